// Round 3
// baseline (115.834 us; speedup 1.0000x reference)
//
#include <hip/hip_runtime.h>

#define NT 10          // trees
#define NL 16          // leaves per tree
#define NN 31          // nodes per tree
#define DD 256         // hidden dim
#define G4 1024        // 4*D gates
#define NNODES (NT*NN) // 310
#define NPATH (NT*NL)  // 160
#define NB 4096

// Monotone per-(step,tree,producer) arrival words (zero-init at load; live in
// __device__ space so they survive ws poison; each word +1 per launch).
// Producer block (t,d4) bumps ONLY g_tf[s][t][d4] (private word -> no shared
// RMW serialization). Consumer reads bases[j] = g_tf[2][t][j] at entry: g_tf[2]
// cannot advance until all 4 team blocks passed the step-1/2 barriers, which
// requires them all to have entered and read their bases -> entry-stable,
// launch-generation-free, graph-replay-safe. 128 B per tree keeps lines apart.
__device__ unsigned g_tf[3][NT][32];

__device__ __forceinline__ float sigf(float x)   { return 1.0f / (1.0f + __expf(-x)); }
__device__ __forceinline__ float tanh_f(float x) { return 2.0f / (1.0f + __expf(-2.0f*x)) - 1.0f; }

__device__ __forceinline__ void co_store(float* p, float v) {
    union { float f; unsigned u; } c; c.f = v;
    __hip_atomic_store((unsigned*)p, c.u, __ATOMIC_RELAXED, __HIP_MEMORY_SCOPE_AGENT);
}

// ---------------------------------------------------------------------------
// K1: nodeproj. xg[n][j] = emb[n].Wih[j] + bih[j] + bhh[j]
// 256 blocks = (mt 0..15 [20 nodes]) x (nt 0..15 [64 W rows]). Proven ~3 us.
// ---------------------------------------------------------------------------
__global__ __launch_bounds__(256) void k_nodeproj(
    const float* __restrict__ emb, const float* __restrict__ Wih,
    const float* __restrict__ bih, const float* __restrict__ bhh,
    float* __restrict__ xg)
{
    __shared__ float smem[20 * 260 + 20 * 4 * 64];
    float4* es4 = (float4*)smem;
    float*  ps  = smem + 20 * 260;

    const int tid = threadIdx.x;
    const int nt  = blockIdx.x & 15;
    const int mt  = blockIdx.x >> 4;
    const int kq  = tid >> 6;
    const int w   = tid & 63;

    const float4* W4 = (const float4*)Wih + (size_t)(nt * 64 + w) * 64 + kq * 16;
    float4 wr[16];
    #pragma unroll
    for (int j = 0; j < 16; ++j) wr[j] = W4[j];

    const float4* emb4 = (const float4*)emb;
    #pragma unroll
    for (int r = 0; r < 5; ++r) {
        int idx = tid + 256 * r;                  // 0..1279
        int m = idx >> 6, q = idx & 63;
        int n = mt * 20 + m;
        es4[m * 65 + q] = (n < NNODES) ? emb4[(size_t)n * 64 + q]
                                       : make_float4(0.f, 0.f, 0.f, 0.f);
    }
    __syncthreads();

    float acc[20];
    #pragma unroll
    for (int m = 0; m < 20; ++m) acc[m] = 0.f;
    #pragma unroll
    for (int j = 0; j < 16; ++j) {
        float4 wv = wr[j];
        #pragma unroll
        for (int m = 0; m < 20; ++m) {
            float4 h = es4[m * 65 + kq * 16 + j];
            acc[m] = fmaf(wv.x, h.x, fmaf(wv.y, h.y,
                     fmaf(wv.z, h.z, fmaf(wv.w, h.w, acc[m]))));
        }
    }
    #pragma unroll
    for (int m = 0; m < 20; ++m) ps[(m * 4 + kq) * 64 + w] = acc[m];
    __syncthreads();

    const int nl   = tid & 63;
    const int msub = tid >> 6;
    const int j    = nt * 64 + nl;
    const float bsum = bih[j] + bhh[j];
    #pragma unroll
    for (int r = 0; r < 5; ++r) {
        int m = msub * 5 + r;
        int n = mt * 20 + m;
        float s = ps[(m * 4 + 0) * 64 + nl] + ps[(m * 4 + 1) * 64 + nl]
                + ps[(m * 4 + 2) * 64 + nl] + ps[(m * 4 + 3) * 64 + nl];
        if (n < NNODES) xg[(size_t)n * G4 + j] = s + bsum;
    }
}

// ---------------------------------------------------------------------------
// K2: all 4 LSTM steps, tree-structured, 4-BLOCK TEAMS.
// Grid: 40 blocks = 10 trees x 4 d-slices, 512 threads each.
// Block (t,d4) owns 64 d-cols -> 256 W_hh rows (4 gates x 64 cols), all
// register-stationary (2 row-quarters/thread = 32 float4). Step s consumes
// 2^(s-1) h rows and spawns 2^s. h exchange among only 4 blocks per tree via
// MALL relaxed stores; per-producer flag words (no shared-line RMWs); wave0
// polls 4 words with ballot. c never crosses blocks (LDS ping-pong).
// ---------------------------------------------------------------------------
__global__ __launch_bounds__(512) void k_treesteps(
    const float* __restrict__ xg, const float* __restrict__ Whh,
    float* __restrict__ h1g, float* __restrict__ h2g,
    float* __restrict__ h3g, float* __restrict__ h4g)
{
    __shared__ float hs[8 * DD];        // input h rows (full width), max L=8
    __shared__ float ps[8 * 4 * DD];    // partials: (parent, kq) x 256 rows
    __shared__ float cbuf[2][8 * 64];   // c ping-pong, this block's 64 cols

    const int tid = threadIdx.x;
    const int t   = blockIdx.x >> 2;    // tree
    const int d4  = blockIdx.x & 3;     // d-slice (64 cols)
    const int kq  = tid >> 7;           // K quarter (64 cols of h)
    const int u   = tid & 127;          // row-pair id: local rows u, u+128
    const int c   = tid & 63;           // col within slice
    const int q0  = tid >> 6;           // child id base (0..7)

    // Entry-stable bases for the poll targets (one per producer word).
    unsigned mybase = 0;
    if (tid < 4)
        mybase = __hip_atomic_load(&g_tf[2][t][tid],
            __ATOMIC_RELAXED, __HIP_MEMORY_SCOPE_AGENT);

    // ---- Entry prefetch #1: W_hh slice (256 rows x 256) -> registers.
    // local row r: gate g = r>>6, col = r&63; global row = g*256 + d4*64 + col
    float4 wreg[2][16];
    #pragma unroll
    for (int rq = 0; rq < 2; ++rq) {
        int r    = u + 128 * rq;
        int grow = (r >> 6) * 256 + d4 * 64 + (r & 63);
        const float4* Wp = (const float4*)Whh + (size_t)grow * 64 + kq * 16;
        #pragma unroll
        for (int j = 0; j < 16; ++j) wreg[rq][j] = Wp[j];
    }

    // ---- Entry prefetch #2: xn gate biases for steps 1..4.
    // Step-s epilogue: thread handles child q = q0 (+8 for s=4 half 1), col c.
    float xnv[4][2][4];
    #pragma unroll
    for (int s = 1; s <= 4; ++s) {
        #pragma unroll
        for (int h = 0; h < 2; ++h) {
            xnv[s-1][h][0] = xnv[s-1][h][1] = 0.f;
            xnv[s-1][h][2] = xnv[s-1][h][3] = 0.f;
        }
        int nact = (s == 4) ? 512 : (64 << s);
        if (tid < nact) {
            int node = (1 << s) - 1 + q0;
            const float* xn = xg + (size_t)(t * NN + node) * G4 + d4 * 64 + c;
            xnv[s-1][0][0] = xn[0];
            xnv[s-1][0][1] = xn[256];
            xnv[s-1][0][2] = xn[512];
            xnv[s-1][0][3] = xn[768];
        }
        if (s == 4) {
            int node = 15 + q0 + 8;
            const float* xn = xg + (size_t)(t * NN + node) * G4 + d4 * 64 + c;
            xnv[3][1][0] = xn[0];
            xnv[3][1][1] = xn[256];
            xnv[3][1][2] = xn[512];
            xnv[3][1][3] = xn[768];
        }
    }

    // ---- Root step: elementwise, full width (h(-1)=c(-1)=0), no GEMM.
    if (tid < 256) {
        const float* xr = xg + (size_t)(t * NN) * G4;
        float r_i = xr[tid], r_g = xr[512 + tid], r_o = xr[768 + tid];
        float c0 = sigf(r_i) * tanh_f(r_g);
        hs[tid]  = sigf(r_o) * tanh_f(c0);
        int lc = tid - d4 * 64;
        if (lc >= 0 && lc < 64) cbuf[0][lc] = c0;
    }
    __syncthreads();

    float* hout[3] = { h1g, h2g, h3g };
    const float* hin[3] = { h1g, h2g, h3g };

    #pragma unroll
    for (int s = 1; s <= 4; ++s) {
        const int L = 1 << (s - 1);                // input rows per tree

        if (s > 1) {
            // wait for all 4 team blocks' step-(s-1) h rows
            if (tid < 64) {
                for (;;) {
                    bool ok = true;
                    if (tid < 4)
                        ok = __hip_atomic_load(&g_tf[s - 2][t][tid],
                                __ATOMIC_RELAXED, __HIP_MEMORY_SCOPE_AGENT)
                             > mybase;
                    if (__all(ok)) break;
                    __builtin_amdgcn_s_sleep(1);
                }
            }
            __syncthreads();
            // stage L rows x 256 floats = L*128 u64 into hs
            const unsigned long long* src =
                (const unsigned long long*)(hin[s - 2] + (size_t)t * L * DD);
            const int n64 = L * 128;               // 256 / 512 / 1024
            unsigned long long raw0 = 0, raw1 = 0;
            if (tid < n64)
                raw0 = __hip_atomic_load(src + tid,
                    __ATOMIC_RELAXED, __HIP_MEMORY_SCOPE_AGENT);
            if (512 + tid < n64)
                raw1 = __hip_atomic_load(src + 512 + tid,
                    __ATOMIC_RELAXED, __HIP_MEMORY_SCOPE_AGENT);
            float2* hs2 = (float2*)hs;
            if (tid < n64) {
                union { unsigned long long u; float2 f; } cv; cv.u = raw0;
                hs2[tid] = cv.f;
            }
            if (512 + tid < n64) {
                union { unsigned long long u; float2 f; } cv; cv.u = raw1;
                hs2[512 + tid] = cv.f;
            }
            __syncthreads();
        }

        // GEMM: for both owned row-quarters, acc[rq][p] = <W row q., h[p] q.>
        const float4* hs4 = (const float4*)hs;
        float acc[2][8];
        #pragma unroll
        for (int p = 0; p < 8; ++p) { acc[0][p] = 0.f; acc[1][p] = 0.f; }
        #pragma unroll
        for (int j = 0; j < 16; ++j) {
            float4 w0 = wreg[0][j], w1 = wreg[1][j];
            #pragma unroll
            for (int p = 0; p < L; ++p) {
                float4 h = hs4[p * 64 + kq * 16 + j];     // uniform broadcast
                acc[0][p] = fmaf(w0.x, h.x, fmaf(w0.y, h.y,
                            fmaf(w0.z, h.z, fmaf(w0.w, h.w, acc[0][p]))));
                acc[1][p] = fmaf(w1.x, h.x, fmaf(w1.y, h.y,
                            fmaf(w1.z, h.z, fmaf(w1.w, h.w, acc[1][p]))));
            }
        }
        #pragma unroll
        for (int p = 0; p < L; ++p) {
            ps[((p << 2) | kq) * 256 + u]       = acc[0][p];
            ps[((p << 2) | kq) * 256 + u + 128] = acc[1][p];
        }
        __syncthreads();

        // Epilogue: children q (local rows g*64+c), sum 4 quarters, gates.
        const int halves = (s == 4) ? 2 : 1;
        #pragma unroll
        for (int hh = 0; hh < halves; ++hh) {
            int q = q0 + 8 * hh;
            bool act = (hh == 1) || (tid < (64 << s));
            if (act) {
                int p = q >> 1;
                float g0 = 0.f, g1 = 0.f, g2 = 0.f, g3 = 0.f;
                #pragma unroll
                for (int k = 0; k < 4; ++k) {
                    const float* pp = ps + ((p << 2) | k) * 256;
                    g0 += pp[c]; g1 += pp[64 + c];
                    g2 += pp[128 + c]; g3 += pp[192 + c];
                }
                float gi = g0 + xnv[s - 1][hh][0];
                float gf = g1 + xnv[s - 1][hh][1];
                float gg = g2 + xnv[s - 1][hh][2];
                float go = g3 + xnv[s - 1][hh][3];
                float cin = cbuf[(s - 1) & 1][p * 64 + c];
                float cn  = sigf(gf) * cin + sigf(gi) * tanh_f(gg);
                float hn  = sigf(go) * tanh_f(cn);
                if (s < 4) {
                    cbuf[s & 1][q * 64 + c] = cn;
                    co_store(hout[s - 1] + (size_t)(t * 2 * L + q) * DD
                                         + d4 * 64 + c, hn);
                } else {
                    h4g[(size_t)(t * NL + q) * DD + d4 * 64 + c] = hn;
                }
            }
        }

        if (s < 4) {
            // drain this block's coherent stores, then bump private word
            __syncthreads();
            if (tid == 0)
                __hip_atomic_fetch_add(&g_tf[s - 1][t][d4], 1u,
                    __ATOMIC_RELAXED, __HIP_MEMORY_SCOPE_AGENT);
        }
    }
}

// ---------------------------------------------------------------------------
// K3: scatter out[b,t,:] = h4[t*16 + argmax(cross[b,t,:]), :]
// 640 blocks x 64 rows: LDS-staged leaf argmax, then fat 16-iter row copy.
// ---------------------------------------------------------------------------
__global__ __launch_bounds__(256) void k_scatter(
    const float* __restrict__ cross, const float* __restrict__ htab,
    float* __restrict__ out)
{
    __shared__ float cls[1024];
    __shared__ int   leafs[64];
    const int tid = threadIdx.x;
    const size_t r0 = (size_t)blockIdx.x * 64;

    #pragma unroll
    for (int k = 0; k < 4; ++k)
        cls[tid + 256 * k] = cross[r0 * 16 + tid + 256 * k];
    __syncthreads();

    if (tid < 64) {
        int leaf = 0;
        #pragma unroll
        for (int l = 15; l >= 0; --l)
            if (cls[tid * 16 + l] > 0.5f) leaf = l;
        int r = (int)(r0 + (size_t)tid);
        int b = r / NT;
        int t = r - b * NT;
        leafs[tid] = t * 16 + leaf;
    }
    __syncthreads();

    const float4* h4 = (const float4*)htab;
    float4* o4 = (float4*)out;
    const int lane = tid & 63;
    const int sub  = tid >> 6;
    #pragma unroll
    for (int it = 0; it < 16; ++it) {
        int rr = it * 4 + sub;
        o4[(r0 + rr) * 64 + lane] = h4[(size_t)leafs[rr] * 64 + lane];
    }
}

// ---------------------------------------------------------------------------
extern "C" void kernel_launch(void* const* d_in, const int* in_sizes, int n_in,
                              void* d_out, int out_size, void* d_ws, size_t ws_size,
                              hipStream_t stream)
{
    const float* cross = (const float*)d_in[0];
    const float* emb   = (const float*)d_in[1];
    const float* Wih   = (const float*)d_in[2];
    const float* Whh   = (const float*)d_in[3];
    const float* bih   = (const float*)d_in[4];
    const float* bhh   = (const float*)d_in[5];
    float* out = (float*)d_out;

    float* ws = (float*)d_ws;
    float* xg = ws;                          // 310*1024
    float* h1 = xg + (size_t)NNODES * G4;    // 20*256
    float* h2 = h1 + 20 * DD;                // 40*256
    float* h3 = h2 + 40 * DD;                // 80*256
    float* h4 = h3 + 80 * DD;                // 160*256

    hipLaunchKernelGGL(k_nodeproj, dim3(256), dim3(256), 0, stream,
                       emb, Wih, bih, bhh, xg);
    hipLaunchKernelGGL(k_treesteps, dim3(40), dim3(512), 0, stream,
                       xg, Whh, h1, h2, h3, h4);
    hipLaunchKernelGGL(k_scatter, dim3(640), dim3(256), 0, stream,
                       cross, h4, out);
}